// Round 1
// baseline (257.613 us; speedup 1.0000x reference)
//
#include <hip/hip_runtime.h>
#include <hip/hip_bf16.h>

// Problem constants
#define LNUM 8
#define ENUM 8
#define DDIM 256
#define BSZ  16384
#define H1N  64
#define H2N  32

// Tiling
#define BT   64     // rows per block
#define NTHR 512    // 8 waves

// LDS pitches (in u16 elements) -- all row strides are multiples of 8 elems (16 B)
#define PX   264    // x tile      (D + 8)
#define PW1  264    // W1 tile     (D + 8)
#define PH1  72     // h1 tile     (H1 + 8)
#define PW2  72     // W2 tile     (H1 + 8)
#define PH2  40     // h2 tile     (H2 + 8)
#define PW3  40     // W3 tile     (H2 + 8)
#define PSW  9      // softmax weights pitch (floats)

typedef float f32x4 __attribute__((ext_vector_type(4)));
typedef unsigned short u16x8 __attribute__((ext_vector_type(8)));
typedef __bf16 bf16x8 __attribute__((ext_vector_type(8)));

// Round-to-nearest-even f32 -> bf16 (truncation would add a coherent -0.2%
// bias per GEMM: 24 GEMMs deep that's a guaranteed accuracy fail).
static __device__ __forceinline__ unsigned short f2bf(float f) {
    unsigned u = __builtin_bit_cast(unsigned, f);
    u += 0x7fffu + ((u >> 16) & 1u);
    return (unsigned short)(u >> 16);
}

static __device__ __forceinline__ f32x4 mfma16(u16x8 a, u16x8 b, f32x4 c) {
    return __builtin_amdgcn_mfma_f32_16x16x32_bf16(
        __builtin_bit_cast(bf16x8, a), __builtin_bit_cast(bf16x8, b), c, 0, 0, 0);
}

// ---------------------------------------------------------------------------
// Kernel 1: convert W1/W2/W3 fp32 -> bf16 (RNE) into workspace.
// Ranges (in 8-elem chunks): W1 131072, W2 16384, W3 65536 -> 212992 threads.
// ---------------------------------------------------------------------------
__global__ __launch_bounds__(256) void cvt_w_bf16(
    const float* __restrict__ w1, const float* __restrict__ w2,
    const float* __restrict__ w3, unsigned short* __restrict__ ws)
{
    int gid = blockIdx.x * 256 + threadIdx.x;
    const float* src;
    unsigned short* dst;
    int off;
    if (gid < 131072) {
        src = w1; dst = ws; off = gid * 8;
    } else if (gid < 131072 + 16384) {
        src = w2; dst = ws + 1048576; off = (gid - 131072) * 8;
    } else {
        src = w3; dst = ws + 1048576 + 131072; off = (gid - 147456) * 8;
    }
    float4 a = *(const float4*)(src + off);
    float4 b = *(const float4*)(src + off + 4);
    u16x8 p;
    p[0] = f2bf(a.x); p[1] = f2bf(a.y); p[2] = f2bf(a.z); p[3] = f2bf(a.w);
    p[4] = f2bf(b.x); p[5] = f2bf(b.y); p[6] = f2bf(b.z); p[7] = f2bf(b.w);
    *(u16x8*)(dst + off) = p;
}

// ---------------------------------------------------------------------------
// Kernel 2: fully fused 8-layer x 8-expert MoE MLP.
// One block = 64 rows of the batch, resident across all layers (x never
// leaves the CU between layers). 8 waves: wave w -> (wm = w&3) 16-row m-tile,
// (wn = w>>2) column half. x held in registers as A-fragments; combined
// output accumulated in registers (softmax weight folded into h2 rows, so
// GEMM3's MFMA performs the expert combine directly in fp32).
// ---------------------------------------------------------------------------
__global__ __launch_bounds__(NTHR, 2) void moe_fused(
    const float* __restrict__ src, const unsigned short* __restrict__ W1b,
    const float* __restrict__ b1, const unsigned short* __restrict__ W2b,
    const float* __restrict__ b2, const unsigned short* __restrict__ W3b,
    const float* __restrict__ b3, const float* __restrict__ masks,
    float* __restrict__ out)
{
    __shared__ __align__(16) unsigned short Xlds[BT * PX];     // 33792 B
    __shared__ __align__(16) unsigned short W1lds[H1N * PW1];  // 33792 B
    __shared__ __align__(16) unsigned short W2lds[H2N * PW2];  //  4608 B
    __shared__ __align__(16) unsigned short W3lds[DDIM * PW3]; // 20480 B
    __shared__ __align__(16) unsigned short H1lds[BT * PH1];   //  9216 B
    __shared__ __align__(16) unsigned short H2lds[BT * PH2];   //  5120 B
    __shared__ float SWlds[BT * PSW];                          //  2304 B
    __shared__ float B3lds[ENUM * DDIM];                       //  8192 B
    __shared__ float B1lds[ENUM * H1N];                        //  2048 B
    __shared__ float B2lds[ENUM * H2N];                        //  1024 B

    const int tid  = threadIdx.x;
    const int lane = tid & 63;
    const int w    = tid >> 6;
    const int wm   = w & 3;       // m-tile (16 rows)
    const int wn   = w >> 2;      // column half
    const int n15  = lane & 15;
    const int q    = lane >> 4;
    const int b0   = blockIdx.x * BT;

    // ---- stage layer-0 x into LDS as bf16 ----
    #pragma unroll
    for (int i = 0; i < 4; ++i) {
        int o = (i * NTHR + tid) * 8;          // elem in 64x256
        int r = o >> 8, c = o & 255;
        const float* p = src + (size_t)(b0 + r) * DDIM + c;
        float4 f0 = *(const float4*)(p);
        float4 f1 = *(const float4*)(p + 4);
        u16x8 pk;
        pk[0] = f2bf(f0.x); pk[1] = f2bf(f0.y); pk[2] = f2bf(f0.z); pk[3] = f2bf(f0.w);
        pk[4] = f2bf(f1.x); pk[5] = f2bf(f1.y); pk[6] = f2bf(f1.z); pk[7] = f2bf(f1.w);
        *(u16x8*)&Xlds[r * PX + c] = pk;
    }

    f32x4 ACC[8];

    #pragma unroll 1
    for (int l = 0; l < LNUM; ++l) {
        // ---- per-layer staging: softmax(masks), b3/b1/b2 slices ----
        if (tid < 64) {
            const float* mp = masks + ((size_t)l * BSZ + b0 + tid) * ENUM;
            float4 m0 = *(const float4*)mp;
            float4 m1 = *(const float4*)(mp + 4);
            float mv[8] = {m0.x, m0.y, m0.z, m0.w, m1.x, m1.y, m1.z, m1.w};
            float mx = mv[0];
            #pragma unroll
            for (int e = 1; e < 8; ++e) mx = fmaxf(mx, mv[e]);
            float s = 0.f;
            #pragma unroll
            for (int e = 0; e < 8; ++e) { mv[e] = expf(mv[e] - mx); s += mv[e]; }
            float inv = 1.f / s;
            #pragma unroll
            for (int e = 0; e < 8; ++e) SWlds[tid * PSW + e] = mv[e] * inv;
        }
        {
            float4 v = *(const float4*)(b3 + (size_t)l * ENUM * DDIM + tid * 4);
            *(float4*)&B3lds[tid * 4] = v;
        }
        if (tid < 128) {
            float4 v = *(const float4*)(b1 + (size_t)l * ENUM * H1N + tid * 4);
            *(float4*)&B1lds[tid * 4] = v;
        }
        if (tid < 64) {
            float4 v = *(const float4*)(b2 + (size_t)l * ENUM * H2N + tid * 4);
            *(float4*)&B2lds[tid * 4] = v;
        }
        __syncthreads();

        // ---- bias-init: ACC = sum_e softmax_w[row][e] * b3[e][col]  (fp32 VALU) ----
        #pragma unroll
        for (int nt = 0; nt < 8; ++nt) ACC[nt] = (f32x4){0.f, 0.f, 0.f, 0.f};
        #pragma unroll 1
        for (int e = 0; e < ENUM; ++e) {
            float swv[4];
            #pragma unroll
            for (int rg = 0; rg < 4; ++rg)
                swv[rg] = SWlds[(wm * 16 + q * 4 + rg) * PSW + e];
            #pragma unroll
            for (int nt = 0; nt < 8; ++nt) {
                float bv = B3lds[e * DDIM + wn * 128 + nt * 16 + n15];
                #pragma unroll
                for (int rg = 0; rg < 4; ++rg) ACC[nt][rg] += swv[rg] * bv;
            }
        }

        // ---- load persistent x A-fragments (this wave's 16 rows, K=256) ----
        u16x8 xf[8];
        #pragma unroll
        for (int kt = 0; kt < 8; ++kt)
            xf[kt] = *(const u16x8*)&Xlds[(wm * 16 + n15) * PX + q * 8 + kt * 32];

        // ---- expert loop ----
        #pragma unroll 1
        for (int e = 0; e < ENUM; ++e) {
            // stage this expert's weights into padded LDS
            const size_t wb1 = (size_t)(l * ENUM + e) * H1N * DDIM;
            #pragma unroll
            for (int i = 0; i < 4; ++i) {
                int o = (i * NTHR + tid) * 8;
                int r = o >> 8, c = o & 255;
                u16x8 v = *(const u16x8*)(W1b + wb1 + o);
                *(u16x8*)&W1lds[r * PW1 + c] = v;
            }
            const size_t wb2 = (size_t)(l * ENUM + e) * H2N * H1N;
            if (tid < 256) {
                int o = tid * 8;
                int r = o >> 6, c = o & 63;
                u16x8 v = *(const u16x8*)(W2b + wb2 + o);
                *(u16x8*)&W2lds[r * PW2 + c] = v;
            }
            const size_t wb3 = (size_t)(l * ENUM + e) * DDIM * H2N;
            #pragma unroll
            for (int i = 0; i < 2; ++i) {
                int o = (i * NTHR + tid) * 8;
                int r = o >> 5, c = o & 31;
                u16x8 v = *(const u16x8*)(W3b + wb3 + o);
                *(u16x8*)&W3lds[r * PW3 + c] = v;
            }
            __syncthreads();

            // GEMM1: h1 = relu(x @ W1^T + b1)   [16 rows x 32 cols per wave]
            f32x4 a1[2] = {(f32x4){0.f,0.f,0.f,0.f}, (f32x4){0.f,0.f,0.f,0.f}};
            #pragma unroll
            for (int kt = 0; kt < 8; ++kt) {
                #pragma unroll
                for (int nt2 = 0; nt2 < 2; ++nt2) {
                    u16x8 bf = *(const u16x8*)
                        &W1lds[(wn * 32 + nt2 * 16 + n15) * PW1 + q * 8 + kt * 32];
                    a1[nt2] = mfma16(xf[kt], bf, a1[nt2]);
                }
            }
            #pragma unroll
            for (int nt2 = 0; nt2 < 2; ++nt2) {
                float bb = B1lds[e * H1N + wn * 32 + nt2 * 16 + n15];
                #pragma unroll
                for (int rg = 0; rg < 4; ++rg) {
                    float v = fmaxf(a1[nt2][rg] + bb, 0.f);
                    H1lds[(wm * 16 + q * 4 + rg) * PH1 + wn * 32 + nt2 * 16 + n15] = f2bf(v);
                }
            }
            __syncthreads();

            // GEMM2: h2 = relu(h1 @ W2^T + b2) * softmax_w[row]   [16 x 16 per wave]
            f32x4 a2 = (f32x4){0.f, 0.f, 0.f, 0.f};
            #pragma unroll
            for (int kt = 0; kt < 2; ++kt) {
                u16x8 af = *(const u16x8*)&H1lds[(wm * 16 + n15) * PH1 + q * 8 + kt * 32];
                u16x8 bf = *(const u16x8*)&W2lds[(wn * 16 + n15) * PW2 + q * 8 + kt * 32];
                a2 = mfma16(af, bf, a2);
            }
            {
                float bb = B2lds[e * H2N + wn * 16 + n15];
                #pragma unroll
                for (int rg = 0; rg < 4; ++rg) {
                    int row = wm * 16 + q * 4 + rg;
                    float v = fmaxf(a2[rg] + bb, 0.f) * SWlds[row * PSW + e];
                    H2lds[row * PH2 + wn * 16 + n15] = f2bf(v);
                }
            }
            __syncthreads();

            // GEMM3: ACC += (w .* h2) @ W3^T    [16 rows x 128 cols per wave]
            u16x8 af = *(const u16x8*)&H2lds[(wm * 16 + n15) * PH2 + q * 8];
            #pragma unroll
            for (int nt = 0; nt < 8; ++nt) {
                u16x8 bf = *(const u16x8*)
                    &W3lds[(wn * 128 + nt * 16 + n15) * PW3 + q * 8];
                ACC[nt] = mfma16(af, bf, ACC[nt]);
            }
            __syncthreads();   // protect W/H tiles before next expert's staging
        } // experts

        if (l < LNUM - 1) {
            // write x_{l+1} back to LDS (bf16 RNE); layer-top barrier orders it
            #pragma unroll
            for (int nt = 0; nt < 8; ++nt) {
                #pragma unroll
                for (int rg = 0; rg < 4; ++rg) {
                    Xlds[(wm * 16 + q * 4 + rg) * PX + wn * 128 + nt * 16 + n15] =
                        f2bf(ACC[nt][rg]);
                }
            }
        }
    } // layers

    // ---- final store (fp32) ----
    #pragma unroll
    for (int nt = 0; nt < 8; ++nt) {
        #pragma unroll
        for (int rg = 0; rg < 4; ++rg) {
            out[(size_t)(b0 + wm * 16 + q * 4 + rg) * DDIM + wn * 128 + nt * 16 + n15] =
                ACC[nt][rg];
        }
    }
}

extern "C" void kernel_launch(void* const* d_in, const int* in_sizes, int n_in,
                              void* d_out, int out_size, void* d_ws, size_t ws_size,
                              hipStream_t stream) {
    const float* src   = (const float*)d_in[0];
    const float* W1    = (const float*)d_in[1];
    const float* b1    = (const float*)d_in[2];
    const float* W2    = (const float*)d_in[3];
    const float* b2    = (const float*)d_in[4];
    const float* W3    = (const float*)d_in[5];
    const float* b3    = (const float*)d_in[6];
    const float* masks = (const float*)d_in[7];
    float* out = (float*)d_out;
    unsigned short* ws = (unsigned short*)d_ws;   // needs 3,407,872 B

    // weights -> bf16 (re-done every launch: harness re-poisons d_ws)
    hipLaunchKernelGGL(cvt_w_bf16, dim3(832), dim3(256), 0, stream, W1, W2, W3, ws);
    // fused forward: 256 blocks x 64 rows, 512 threads
    hipLaunchKernelGGL(moe_fused, dim3(256), dim3(NTHR), 0, stream,
                       src, ws, b1, ws + 1048576, b2, ws + 1179648, b3, masks, out);
}

// Round 2
// 208.664 us; speedup vs baseline: 1.2346x; 1.2346x over previous
//
#include <hip/hip_runtime.h>
#include <hip/hip_bf16.h>

// Problem constants
#define LNUM 8
#define ENUM 8
#define DDIM 256
#define BSZ  16384
#define H1N  64
#define H2N  32

#define BT   64     // rows per block
#define NTHR 512    // 8 waves

// LDS pitches (u16 elements). All row strides are ODD multiples of 8 elems
// (16B granules) -> conflict-free b128 fragment reads (granule stride odd
// mod 8 cycles all bank groups; 2-way aliasing is free on CDNA4).
#define PX   264    // W1 / x tile (D + 8)   -> 33 granules/row
#define PH1  72     // h1 tile (H1 + 8)      -> 9
#define PW2  72     // W2 tile (H1 + 8)      -> 9
#define PH2  40     // h2 tile (H2 + 8)      -> 5
#define PW3  40     // W3 tile (H2 + 8)      -> 5
#define PSW  9      // softmax weights pitch (floats)

typedef float f32x4 __attribute__((ext_vector_type(4)));
typedef unsigned short u16x8 __attribute__((ext_vector_type(8)));
typedef __bf16 bf16x8 __attribute__((ext_vector_type(8)));

// Round-to-nearest-even f32 -> bf16 (truncation bias compounds over 24 GEMMs).
static __device__ __forceinline__ unsigned short f2bf(float f) {
    unsigned u = __builtin_bit_cast(unsigned, f);
    u += 0x7fffu + ((u >> 16) & 1u);
    return (unsigned short)(u >> 16);
}

static __device__ __forceinline__ f32x4 mfma16(u16x8 a, u16x8 b, f32x4 c) {
    return __builtin_amdgcn_mfma_f32_16x16x32_bf16(
        __builtin_bit_cast(bf16x8, a), __builtin_bit_cast(bf16x8, b), c, 0, 0, 0);
}

// ---------------------------------------------------------------------------
// Kernel 1: convert W1/W2/W3 fp32 -> bf16 (RNE) into workspace (linear layout).
// ---------------------------------------------------------------------------
__global__ __launch_bounds__(256) void cvt_w_bf16(
    const float* __restrict__ w1, const float* __restrict__ w2,
    const float* __restrict__ w3, unsigned short* __restrict__ ws)
{
    int gid = blockIdx.x * 256 + threadIdx.x;
    const float* src;
    unsigned short* dst;
    int off;
    if (gid < 131072) {
        src = w1; dst = ws; off = gid * 8;
    } else if (gid < 131072 + 16384) {
        src = w2; dst = ws + 1048576; off = (gid - 131072) * 8;
    } else {
        src = w3; dst = ws + 1048576 + 131072; off = (gid - 147456) * 8;
    }
    float4 a = *(const float4*)(src + off);
    float4 b = *(const float4*)(src + off + 4);
    u16x8 p;
    p[0] = f2bf(a.x); p[1] = f2bf(a.y); p[2] = f2bf(a.z); p[3] = f2bf(a.w);
    p[4] = f2bf(b.x); p[5] = f2bf(b.y); p[6] = f2bf(b.z); p[7] = f2bf(b.w);
    *(u16x8*)(dst + off) = p;
}

// ---------------------------------------------------------------------------
// Kernel 2: fully fused 8-layer x 8-expert MoE MLP.
// Block = 64 rows, resident across all layers. 8 waves: (wm in {0,1}) 32-row
// half x (wn in {0..3}) column slice. x held as A-fragments in registers
// (32 rows x 256 K = 64 VGPRs/wave); W1 B-frags reused across both M-subtiles
// (halves G1 LDS traffic vs 16-row tiles). Next expert's weights prefetched
// into registers at expert start and ds_written the moment each LDS region is
// freed by a barrier -> no global latency on the barrier critical path,
// single-buffered LDS (87 KB).
// ---------------------------------------------------------------------------
__global__ __launch_bounds__(NTHR, 2) void moe_fused(
    const float* __restrict__ src, const unsigned short* __restrict__ W1g,
    const float* __restrict__ b1, const unsigned short* __restrict__ W2g,
    const float* __restrict__ b2, const unsigned short* __restrict__ W3g,
    const float* __restrict__ b3, const float* __restrict__ masks,
    float* __restrict__ out)
{
    __shared__ __align__(16) unsigned short W1lds[BT * PX];    // 33792 B (also x at layer transitions)
    __shared__ __align__(16) unsigned short W2lds[H2N * PW2];  //  4608 B
    __shared__ __align__(16) unsigned short W3lds[DDIM * PW3]; // 20480 B
    __shared__ __align__(16) unsigned short H1lds[BT * PH1];   //  9216 B
    __shared__ __align__(16) unsigned short H2lds[BT * PH2];   //  5120 B
    __shared__ float SWlds[BT * PSW];                          //  2304 B
    __shared__ float B3lds[ENUM * DDIM];                       //  8192 B
    __shared__ float B1lds[ENUM * H1N];                        //  2048 B
    __shared__ float B2lds[ENUM * H2N];                        //  1024 B
    // total 86784 B -> 1 block/CU

    const int tid  = threadIdx.x;
    const int lane = tid & 63;
    const int w    = tid >> 6;
    const int wm   = w >> 2;        // {0,1}: 32-row half
    const int wn   = w & 3;         // {0..3}: column slice
    const int n15  = lane & 15;
    const int q    = lane >> 4;
    const int b0   = blockIdx.x * BT;
    const int mtG2 = wm * 2 + (wn >> 1);   // G2: 16-row tile {0..3}
    const int ncG2 = (wn & 1) * 16;        // G2: 16-col slice

    u16x8 xf[2][8];      // persistent x A-fragments: 2 M-subtiles x K=256
    f32x4 ACC[2][4];     // output accumulator: 2 M-subtiles x 4 N-subtiles
    u16x8 pf1[4], pf3[2], pf2;   // weight prefetch registers

    // ---- prefetch: global (bf16 ws, linear) -> regs; 1KB chunks per wave ----
    auto pf_issue = [&](int ns) {
        const unsigned short* p1 = W1g + (size_t)ns * 16384;
        #pragma unroll
        for (int i = 0; i < 4; ++i)
            pf1[i] = *(const u16x8*)(p1 + (w + 8 * i) * 512 + lane * 8);
        const unsigned short* p3 = W3g + (size_t)ns * 8192;
        #pragma unroll
        for (int i = 0; i < 2; ++i)
            pf3[i] = *(const u16x8*)(p3 + (w + 8 * i) * 512 + lane * 8);
        if (w < 4)
            pf2 = *(const u16x8*)(W2g + (size_t)ns * 2048 + w * 512 + lane * 8);
    };
    // ---- regs -> padded LDS tiles ----
    auto w1_write = [&]() {
        #pragma unroll
        for (int i = 0; i < 4; ++i) {
            int c = w + 8 * i;
            int r = 2 * c + (lane >> 5), col = (lane & 31) * 8;
            *(u16x8*)&W1lds[r * PX + col] = pf1[i];
        }
    };
    auto w3_write = [&]() {
        #pragma unroll
        for (int i = 0; i < 2; ++i) {
            int c = w + 8 * i;
            int r = 16 * c + (lane >> 2), col = (lane & 3) * 8;
            *(u16x8*)&W3lds[r * PW3 + col] = pf3[i];
        }
    };
    auto w2_write = [&]() {
        if (w < 4) {
            int r = 8 * w + (lane >> 3), col = (lane & 7) * 8;
            *(u16x8*)&W2lds[r * PW2 + col] = pf2;
        }
    };

    // ---- per-layer staging: softmax(masks), bias slices ----
    auto stage_layer = [&](int l) {
        if (tid < 64) {
            const float* mp = masks + ((size_t)l * BSZ + b0 + tid) * ENUM;
            float4 m0 = *(const float4*)mp;
            float4 m1 = *(const float4*)(mp + 4);
            float mv[8] = {m0.x, m0.y, m0.z, m0.w, m1.x, m1.y, m1.z, m1.w};
            float mx = mv[0];
            #pragma unroll
            for (int e = 1; e < 8; ++e) mx = fmaxf(mx, mv[e]);
            float s = 0.f;
            #pragma unroll
            for (int e = 0; e < 8; ++e) { mv[e] = expf(mv[e] - mx); s += mv[e]; }
            float inv = 1.f / s;
            #pragma unroll
            for (int e = 0; e < 8; ++e) SWlds[tid * PSW + e] = mv[e] * inv;
        }
        *(float4*)&B3lds[tid * 4] =
            *(const float4*)(b3 + (size_t)l * ENUM * DDIM + tid * 4);
        if (tid < 128)
            *(float4*)&B1lds[tid * 4] =
                *(const float4*)(b1 + (size_t)l * ENUM * H1N + tid * 4);
        if (tid < 64)
            *(float4*)&B2lds[tid * 4] =
                *(const float4*)(b2 + (size_t)l * ENUM * H2N + tid * 4);
    };

    // ---- ACC = sum_e softmax_w[row][e] * b3[e][col] (fp32 VALU, once/layer) ----
    auto acc_init = [&]() {
        #pragma unroll
        for (int mt = 0; mt < 2; ++mt)
            #pragma unroll
            for (int nt = 0; nt < 4; ++nt) ACC[mt][nt] = (f32x4){0.f,0.f,0.f,0.f};
        #pragma unroll 1
        for (int e2 = 0; e2 < ENUM; ++e2) {
            float swv[2][4];
            #pragma unroll
            for (int mt = 0; mt < 2; ++mt)
                #pragma unroll
                for (int rg = 0; rg < 4; ++rg)
                    swv[mt][rg] = SWlds[(wm*32 + mt*16 + q*4 + rg) * PSW + e2];
            #pragma unroll
            for (int nt = 0; nt < 4; ++nt) {
                float bv = B3lds[e2 * DDIM + wn*64 + nt*16 + n15];
                #pragma unroll
                for (int mt = 0; mt < 2; ++mt)
                    #pragma unroll
                    for (int rg = 0; rg < 4; ++rg)
                        ACC[mt][nt][rg] += swv[mt][rg] * bv;
            }
        }
    };

    auto xf_read = [&]() {
        #pragma unroll
        for (int mt = 0; mt < 2; ++mt)
            #pragma unroll
            for (int kt = 0; kt < 8; ++kt)
                xf[mt][kt] = *(const u16x8*)
                    &W1lds[(wm*32 + mt*16 + n15) * PX + q*8 + kt*32];
    };
    auto x_write = [&]() {   // ACC -> bf16 x in W1lds (region free after B3)
        #pragma unroll
        for (int mt = 0; mt < 2; ++mt)
            #pragma unroll
            for (int nt = 0; nt < 4; ++nt)
                #pragma unroll
                for (int rg = 0; rg < 4; ++rg)
                    W1lds[(wm*32 + mt*16 + q*4 + rg) * PX + wn*64 + nt*16 + n15] =
                        f2bf(ACC[mt][nt][rg]);
    };

    // ================= prologue =================
    pf_issue(0);
    // stage layer-0 x into W1lds as bf16
    #pragma unroll
    for (int i = 0; i < 4; ++i) {
        int o = (i * NTHR + tid) * 8;
        int r = o >> 8, c = o & 255;
        const float* p = src + (size_t)(b0 + r) * DDIM + c;
        float4 f0 = *(const float4*)(p);
        float4 f1 = *(const float4*)(p + 4);
        u16x8 pk;
        pk[0] = f2bf(f0.x); pk[1] = f2bf(f0.y); pk[2] = f2bf(f0.z); pk[3] = f2bf(f0.w);
        pk[4] = f2bf(f1.x); pk[5] = f2bf(f1.y); pk[6] = f2bf(f1.z); pk[7] = f2bf(f1.w);
        *(u16x8*)&W1lds[r * PX + c] = pk;
    }
    stage_layer(0);
    w2_write();
    w3_write();
    __syncthreads();          // x, biases, W2/W3 visible
    xf_read();
    __syncthreads();          // xf reads done before W1 overwrite
    w1_write();
    acc_init();
    __syncthreads();          // W1 visible

    // ================= fused expert-layer loop =================
    #pragma unroll 1
    for (int s = 0; s < LNUM * ENUM; ++s) {
        const int e = s & 7, l = s >> 3;
        if (s < 63) pf_issue(s + 1);

        // ---- G1: h1 = relu(x @ W1^T + b1); B-frag shared by both M-subtiles ----
        f32x4 a1[2] = {(f32x4){0.f,0.f,0.f,0.f}, (f32x4){0.f,0.f,0.f,0.f}};
        #pragma unroll
        for (int kt = 0; kt < 8; ++kt) {
            u16x8 bf = *(const u16x8*)&W1lds[(wn*16 + n15) * PX + q*8 + kt*32];
            a1[0] = mfma16(xf[0][kt], bf, a1[0]);
            a1[1] = mfma16(xf[1][kt], bf, a1[1]);
        }
        {
            float bb = B1lds[e * H1N + wn*16 + n15];
            #pragma unroll
            for (int mt = 0; mt < 2; ++mt)
                #pragma unroll
                for (int rg = 0; rg < 4; ++rg) {
                    float v = fmaxf(a1[mt][rg] + bb, 0.f);
                    H1lds[(wm*32 + mt*16 + q*4 + rg) * PH1 + wn*16 + n15] = f2bf(v);
                }
        }
        __syncthreads();                       // B1: h1 ready, W1 free
        if (e < 7) w1_write();                 // stage W1(e+1)

        // ---- G2: h2 = relu(h1 @ W2^T + b2) * softmax_w[row] ----
        f32x4 a2 = (f32x4){0.f, 0.f, 0.f, 0.f};
        #pragma unroll
        for (int kt = 0; kt < 2; ++kt) {
            u16x8 af = *(const u16x8*)&H1lds[(mtG2*16 + n15) * PH1 + q*8 + kt*32];
            u16x8 bf = *(const u16x8*)&W2lds[(ncG2 + n15) * PW2 + q*8 + kt*32];
            a2 = mfma16(af, bf, a2);
        }
        {
            float bb = B2lds[e * H2N + ncG2 + n15];
            #pragma unroll
            for (int rg = 0; rg < 4; ++rg) {
                int row = mtG2*16 + q*4 + rg;
                float v = fmaxf(a2[rg] + bb, 0.f) * SWlds[row * PSW + e];
                H2lds[row * PH2 + ncG2 + n15] = f2bf(v);
            }
        }
        __syncthreads();                       // B2: h2 ready, W2 free
        if (s < 63) w2_write();                // stage W2(next)

        // ---- G3: ACC += (w .* h2) @ W3^T ----
        {
            u16x8 af0 = *(const u16x8*)&H2lds[(wm*32 + n15) * PH2 + q*8];
            u16x8 af1 = *(const u16x8*)&H2lds[(wm*32 + 16 + n15) * PH2 + q*8];
            #pragma unroll
            for (int nt = 0; nt < 4; ++nt) {
                u16x8 bf = *(const u16x8*)&W3lds[(wn*64 + nt*16 + n15) * PW3 + q*8];
                ACC[0][nt] = mfma16(af0, bf, ACC[0][nt]);
                ACC[1][nt] = mfma16(af1, bf, ACC[1][nt]);
            }
        }
        __syncthreads();                       // B3: h2/W3 consumed
        if (s < 63) w3_write();                // stage W3(next)

        // ---- layer transition ----
        if (e == 7 && l < LNUM - 1) {
            x_write();                         // ACC -> x in W1lds (pf1 held back)
            __syncthreads();
            xf_read();
            stage_layer(l + 1);
            __syncthreads();                   // xf read done; biases visible
            w1_write();                        // now stage W1(l+1, 0)
            acc_init();
            __syncthreads();                   // W1 visible
        }
    }

    // ================= final store (fp32) =================
    #pragma unroll
    for (int mt = 0; mt < 2; ++mt)
        #pragma unroll
        for (int nt = 0; nt < 4; ++nt)
            #pragma unroll
            for (int rg = 0; rg < 4; ++rg)
                out[(size_t)(b0 + wm*32 + mt*16 + q*4 + rg) * DDIM
                    + wn*64 + nt*16 + n15] = ACC[mt][nt][rg];
}

extern "C" void kernel_launch(void* const* d_in, const int* in_sizes, int n_in,
                              void* d_out, int out_size, void* d_ws, size_t ws_size,
                              hipStream_t stream) {
    const float* src   = (const float*)d_in[0];
    const float* W1    = (const float*)d_in[1];
    const float* b1    = (const float*)d_in[2];
    const float* W2    = (const float*)d_in[3];
    const float* b2    = (const float*)d_in[4];
    const float* W3    = (const float*)d_in[5];
    const float* b3    = (const float*)d_in[6];
    const float* masks = (const float*)d_in[7];
    float* out = (float*)d_out;
    unsigned short* ws = (unsigned short*)d_ws;   // needs 3,407,872 B

    hipLaunchKernelGGL(cvt_w_bf16, dim3(832), dim3(256), 0, stream, W1, W2, W3, ws);
    hipLaunchKernelGGL(moe_fused, dim3(BSZ / BT), dim3(NTHR), 0, stream,
                       src, ws, b1, ws + 1048576, b2, ws + 1179648, b3, masks, out);
}